// Round 1
// baseline (1274.657 us; speedup 1.0000x reference)
//
#include <hip/hip_runtime.h>
#include <math.h>

// Problem constants (match reference)
constexpr int CH         = 64;
constexpr int N_USERS    = 50000;
constexpr int N_ENTITIES = 100000;
constexpr int N_FACTORS  = 4;
constexpr int N_RELM1    = 8;     // N_REL - 1
constexpr int N_EDGES    = 1500000;
constexpr int NNZ        = 800000;

// ---------------------------------------------------------------------------
// 64-lane butterfly reduction: all lanes end with the full sum.
__device__ __forceinline__ float waveReduceSum(float v) {
    #pragma unroll
    for (int off = 32; off > 0; off >>= 1)
        v += __shfl_xor(v, off, 64);
    return v;
}

// ---------------------------------------------------------------------------
// Edge message scatter: agg[head[e]][c] += ent[tail[e]][c] * weight[etype[e]-1][c]
// One thread per (edge, channel); wave = one edge, coalesced gather + atomic.
__global__ __launch_bounds__(256)
void edge_scatter(const float* __restrict__ ent,
                  const float* __restrict__ weight,
                  const int*   __restrict__ head,
                  const int*   __restrict__ tail,
                  const int*   __restrict__ etype,
                  float*       __restrict__ agg) {
    long long t = (long long)blockIdx.x * blockDim.x + threadIdx.x;
    int e = (int)(t >> 6);
    int c = (int)(t & 63);
    if (e >= N_EDGES) return;
    int h  = head[e];
    int tl = tail[e];
    int et = etype[e] - 1;
    float v = ent[tl * CH + c] * weight[et * CH + c];
    atomicAdd(&agg[h * CH + c], v);
}

// ---------------------------------------------------------------------------
// User interaction scatter: uagg[row[i]][c] += vals[i] * ent[col[i]][c]
__global__ __launch_bounds__(256)
void nnz_scatter(const float* __restrict__ ent,
                 const float* __restrict__ vals,
                 const int*   __restrict__ rows,
                 const int*   __restrict__ cols,
                 float*       __restrict__ uagg) {
    long long t = (long long)blockIdx.x * blockDim.x + threadIdx.x;
    int i = (int)(t >> 6);
    int c = (int)(t & 63);
    if (i >= NNZ) return;
    int r  = rows[i];
    int cl = cols[i];
    float v = vals[i] * ent[cl * CH + c];
    atomicAdd(&uagg[r * CH + c], v);
}

// ---------------------------------------------------------------------------
// Entity finalize: in-place L2-normalize each row of agg (the /cnt cancels
// under normalization), accumulate into residual output.
__global__ __launch_bounds__(256)
void entity_finalize(float* __restrict__ agg,
                     float* __restrict__ res) {
    int row  = blockIdx.x * 4 + (threadIdx.x >> 6);
    int lane = threadIdx.x & 63;
    if (row >= N_ENTITIES) return;
    int idx = row * CH + lane;
    float x = agg[idx];
    float s = waveReduceSum(x * x);
    float y = x / fmaxf(sqrtf(s), 1e-12f);
    agg[idx] = y;        // becomes next hop's entity_emb
    res[idx] += y;
}

// ---------------------------------------------------------------------------
// User finalize: score = softmax(ucur @ latent^T); mix = score @ dw;
// un = uagg*(1+mix); L2-normalize; accumulate residual. In-place in uagg.
__global__ __launch_bounds__(256)
void user_finalize(const float* __restrict__ ucur,
                   float*       __restrict__ uagg,
                   const float* __restrict__ latent,
                   const float* __restrict__ dw,
                   float*       __restrict__ res) {
    int row  = blockIdx.x * 4 + (threadIdx.x >> 6);
    int lane = threadIdx.x & 63;
    if (row >= N_USERS) return;
    int idx = row * CH + lane;
    float u = ucur[idx];
    float d0 = waveReduceSum(u * latent[0 * CH + lane]);
    float d1 = waveReduceSum(u * latent[1 * CH + lane]);
    float d2 = waveReduceSum(u * latent[2 * CH + lane]);
    float d3 = waveReduceSum(u * latent[3 * CH + lane]);
    float m  = fmaxf(fmaxf(d0, d1), fmaxf(d2, d3));
    float e0 = expf(d0 - m), e1 = expf(d1 - m), e2 = expf(d2 - m), e3 = expf(d3 - m);
    float inv = 1.0f / (e0 + e1 + e2 + e3);
    float mix = (e0 * dw[0 * CH + lane] + e1 * dw[1 * CH + lane] +
                 e2 * dw[2 * CH + lane] + e3 * dw[3 * CH + lane]) * inv;
    float a  = uagg[idx];
    float un = a * (1.0f + mix);
    float s  = waveReduceSum(un * un);
    float y  = un / fmaxf(sqrtf(s), 1e-12f);
    uagg[idx] = y;       // becomes next hop's user_emb
    res[idx] += y;
}

// ---------------------------------------------------------------------------
// disen_weight = softmax(att, axis=-1) @ weight   (4x8 @ 8x64 -> 4x64)
__global__ void disen_kernel(const float* __restrict__ att,
                             const float* __restrict__ weight,
                             float*       __restrict__ dw) {
    int f = threadIdx.x >> 6;   // 0..3
    int c = threadIdx.x & 63;   // 0..63
    float m = -1e30f;
    #pragma unroll
    for (int j = 0; j < N_RELM1; ++j) m = fmaxf(m, att[f * N_RELM1 + j]);
    float s = 0.0f, w[N_RELM1];
    #pragma unroll
    for (int j = 0; j < N_RELM1; ++j) { w[j] = expf(att[f * N_RELM1 + j] - m); s += w[j]; }
    float acc = 0.0f;
    #pragma unroll
    for (int j = 0; j < N_RELM1; ++j) acc += w[j] * weight[j * CH + c];
    dw[f * CH + c] = acc / s;
}

// ---------------------------------------------------------------------------
// Distance-correlation scalar over the 6 factor pairs (8x8 matrices — tiny).
__global__ void cor_kernel(const float* __restrict__ att,
                           float*       __restrict__ out) {
    if (threadIdx.x != 0 || blockIdx.x != 0) return;
    float cor = 0.0f;
    for (int i = 0; i < N_FACTORS; ++i) {
        for (int j = i + 1; j < N_FACTORS; ++j) {
            const float* t1 = att + i * N_RELM1;
            const float* t2 = att + j * N_RELM1;
            float a[8][8], b[8][8];
            for (int r = 0; r < 8; ++r)
                for (int c = 0; c < 8; ++c) {
                    float da = t1[r] * t1[r] - 2.0f * t1[r] * t1[c] + t1[c] * t1[c];
                    a[r][c] = sqrtf(fmaxf(da, 0.0f) + 1e-8f);
                    float db = t2[r] * t2[r] - 2.0f * t2[r] * t2[c] + t2[c] * t2[c];
                    b[r][c] = sqrtf(fmaxf(db, 0.0f) + 1e-8f);
                }
            float rma[8] = {0}, cma[8] = {0}, rmb[8] = {0}, cmb[8] = {0};
            float ta = 0.0f, tb = 0.0f;
            for (int r = 0; r < 8; ++r)
                for (int c = 0; c < 8; ++c) {
                    rma[r] += a[r][c]; cma[c] += a[r][c]; ta += a[r][c];
                    rmb[r] += b[r][c]; cmb[c] += b[r][c]; tb += b[r][c];
                }
            for (int r = 0; r < 8; ++r) { rma[r] *= 0.125f; rmb[r] *= 0.125f; }
            for (int c = 0; c < 8; ++c) { cma[c] *= 0.125f; cmb[c] *= 0.125f; }
            ta /= 64.0f; tb /= 64.0f;
            float sAB = 0.0f, sAA = 0.0f, sBB = 0.0f;
            for (int r = 0; r < 8; ++r)
                for (int c = 0; c < 8; ++c) {
                    float A = a[r][c] - cma[c] - rma[r] + ta;
                    float B = b[r][c] - cmb[c] - rmb[r] + tb;
                    sAB += A * B; sAA += A * A; sBB += B * B;
                }
            float dAB = sqrtf(fmaxf(sAB / 64.0f, 0.0f) + 1e-8f);
            float dAA = sqrtf(fmaxf(sAA / 64.0f, 0.0f) + 1e-8f);
            float dBB = sqrtf(fmaxf(sBB / 64.0f, 0.0f) + 1e-8f);
            cor += dAB / sqrtf(dAA * dBB + 1e-8f);
        }
    }
    out[0] = cor;
}

// ---------------------------------------------------------------------------
extern "C" void kernel_launch(void* const* d_in, const int* in_sizes, int n_in,
                              void* d_out, int out_size, void* d_ws, size_t ws_size,
                              hipStream_t stream) {
    const float* user_emb   = (const float*)d_in[0];
    const float* entity_emb = (const float*)d_in[1];
    const float* latent     = (const float*)d_in[2];
    const float* weight     = (const float*)d_in[3];
    const float* att        = (const float*)d_in[4];
    const float* ivals      = (const float*)d_in[5];
    const int*   head       = (const int*)d_in[6];
    const int*   tail       = (const int*)d_in[7];
    const int*   etype      = (const int*)d_in[8];
    const int*   irows      = (const int*)d_in[9];
    const int*   icols      = (const int*)d_in[10];

    float* out     = (float*)d_out;
    float* ent_res = out;
    float* usr_res = out + (size_t)N_ENTITIES * CH;
    float* cor_out = out + (size_t)N_ENTITIES * CH + (size_t)N_USERS * CH;

    const size_t ENT_ELEMS = (size_t)N_ENTITIES * CH;   // 6.4M
    const size_t USR_ELEMS = (size_t)N_USERS * CH;      // 3.2M

    float* ws = (float*)d_ws;
    float* Ae = ws;                    // entity agg / emb hop0
    float* Be = Ae + ENT_ELEMS;        // entity agg / emb hop1
    float* Au = Be + ENT_ELEMS;        // user agg / emb hop0
    float* Bu = Au + USR_ELEMS;        // user agg / emb hop1
    float* dw = Bu + USR_ELEMS;        // disen_weight 4x64

    // Zero the accumulators (ws is poisoned 0xAA before every timed launch).
    hipMemsetAsync(Ae, 0, ENT_ELEMS * sizeof(float), stream);
    hipMemsetAsync(Be, 0, ENT_ELEMS * sizeof(float), stream);
    hipMemsetAsync(Au, 0, USR_ELEMS * sizeof(float), stream);
    hipMemsetAsync(Bu, 0, USR_ELEMS * sizeof(float), stream);

    // Residual outputs start at the input embeddings.
    hipMemcpyAsync(ent_res, entity_emb, ENT_ELEMS * sizeof(float),
                   hipMemcpyDeviceToDevice, stream);
    hipMemcpyAsync(usr_res, user_emb, USR_ELEMS * sizeof(float),
                   hipMemcpyDeviceToDevice, stream);

    disen_kernel<<<1, 256, 0, stream>>>(att, weight, dw);
    cor_kernel<<<1, 64, 0, stream>>>(att, cor_out);

    const int edgeBlocks = (int)(((long long)N_EDGES * CH + 255) / 256);
    const int nnzBlocks  = (int)(((long long)NNZ * CH + 255) / 256);
    const int entBlocks  = (N_ENTITIES + 3) / 4;
    const int usrBlocks  = (N_USERS + 3) / 4;

    // ---- Hop 0 (reads input embeddings) ----
    edge_scatter<<<edgeBlocks, 256, 0, stream>>>(entity_emb, weight, head, tail, etype, Ae);
    nnz_scatter<<<nnzBlocks, 256, 0, stream>>>(entity_emb, ivals, irows, icols, Au);
    entity_finalize<<<entBlocks, 256, 0, stream>>>(Ae, ent_res);
    user_finalize<<<usrBlocks, 256, 0, stream>>>(user_emb, Au, latent, dw, usr_res);

    // ---- Hop 1 (reads hop-0 embeddings Ae/Au) ----
    edge_scatter<<<edgeBlocks, 256, 0, stream>>>(Ae, weight, head, tail, etype, Be);
    nnz_scatter<<<nnzBlocks, 256, 0, stream>>>(Ae, ivals, irows, icols, Bu);
    entity_finalize<<<entBlocks, 256, 0, stream>>>(Be, ent_res);
    user_finalize<<<usrBlocks, 256, 0, stream>>>(Au, Bu, latent, dw, usr_res);
}

// Round 2
// 1101.618 us; speedup vs baseline: 1.1571x; 1.1571x over previous
//
#include <hip/hip_runtime.h>
#include <math.h>

// Problem constants (match reference)
constexpr int CH         = 64;
constexpr int N_USERS    = 50000;
constexpr int N_ENTITIES = 100000;
constexpr int N_FACTORS  = 4;
constexpr int N_RELM1    = 8;     // N_REL - 1
constexpr int N_EDGES    = 1500000;
constexpr int NNZ        = 800000;

// ---------------------------------------------------------------------------
__device__ __forceinline__ float waveReduceSum(float v) {
    #pragma unroll
    for (int off = 32; off > 0; off >>= 1)
        v += __shfl_xor(v, off, 64);
    return v;
}

// ---------------------------------------------------------------------------
// CSR build: histogram -> exclusive scan -> fill (bucketed, order-free).
__global__ __launch_bounds__(256)
void hist_kernel(const int* __restrict__ key, int* __restrict__ cnt, int n) {
    int i = blockIdx.x * 256 + threadIdx.x;
    if (i < n) atomicAdd(&cnt[key[i]], 1);
}

// Single-block exclusive scan over n counts; writes off[0..n] and cursor copy.
__global__ __launch_bounds__(1024)
void scan_kernel(const int* __restrict__ cnt, int* __restrict__ off,
                 int* __restrict__ cur, int n) {
    __shared__ int lds[1024];
    int t = threadIdx.x;
    int chunk = (n + 1023) >> 10;
    int lo = t * chunk;
    int hi = min(lo + chunk, n);
    int s = 0;
    for (int i = lo; i < hi; ++i) s += cnt[i];
    lds[t] = s;
    __syncthreads();
    for (int d = 1; d < 1024; d <<= 1) {
        int u = (t >= d) ? lds[t - d] : 0;
        __syncthreads();
        lds[t] += u;
        __syncthreads();
    }
    int run = lds[t] - s;                 // exclusive prefix for this chunk
    if (t == 1023) off[n] = lds[1023];
    for (int i = lo; i < hi; ++i) {
        off[i] = run; cur[i] = run;
        run += cnt[i];
    }
}

// Fill edge buckets with packed (tail | (etype-1)<<20) — one coalesced int
// per edge in the gather loop instead of two random 4B reads.
__global__ __launch_bounds__(256)
void fill_edges(const int* __restrict__ head, const int* __restrict__ tail,
                const int* __restrict__ etype, int* __restrict__ cur,
                int* __restrict__ elist) {
    int e = blockIdx.x * 256 + threadIdx.x;
    if (e >= N_EDGES) return;
    int pos = atomicAdd(&cur[head[e]], 1);
    elist[pos] = tail[e] | ((etype[e] - 1) << 20);
}

__global__ __launch_bounds__(256)
void fill_users(const int* __restrict__ rows, const int* __restrict__ cols,
                const float* __restrict__ vals, int* __restrict__ cur,
                int* __restrict__ ucol, float* __restrict__ uval) {
    int i = blockIdx.x * 256 + threadIdx.x;
    if (i >= NNZ) return;
    int pos = atomicAdd(&cur[rows[i]], 1);
    ucol[pos] = cols[i];
    uval[pos] = vals[i];
}

// ---------------------------------------------------------------------------
// Entity pass: gather incoming-edge messages per row, L2-normalize (the /cnt
// cancels under normalization), write next-hop emb (optional) + residual.
template <bool FIRST, bool STORE>
__global__ __launch_bounds__(256)
void entity_pass(const float* __restrict__ ent_in,
                 const float* __restrict__ weight,
                 const int*   __restrict__ off,
                 const int*   __restrict__ elist,
                 float*       __restrict__ emb_out,
                 float*       __restrict__ res,
                 const float* __restrict__ base) {
    __shared__ float w_lds[N_RELM1 * CH];
    for (int i = threadIdx.x; i < N_RELM1 * CH; i += 256) w_lds[i] = weight[i];
    __syncthreads();
    int row  = blockIdx.x * 4 + (threadIdx.x >> 6);
    int lane = threadIdx.x & 63;
    if (row >= N_ENTITIES) return;
    int lo = off[row], hi = off[row + 1];
    float acc = 0.0f;
    for (int k0 = lo; k0 < hi; k0 += 64) {
        int m = min(64, hi - k0);
        int p = (lane < m) ? elist[k0 + lane] : 0;
        for (int k = 0; k < m; ++k) {
            int pk = __shfl(p, k, 64);
            int tl = pk & 0xFFFFF;
            int et = pk >> 20;
            acc += ent_in[tl * CH + lane] * w_lds[et * CH + lane];
        }
    }
    float s = waveReduceSum(acc * acc);
    float y = acc / fmaxf(sqrtf(s), 1e-12f);
    int idx = row * CH + lane;
    if (STORE) emb_out[idx] = y;
    if (FIRST) res[idx] = base[idx] + y;
    else       res[idx] += y;
}

// ---------------------------------------------------------------------------
// User pass: gather interactions, fuse softmax(score)@dw mix, L2-norm, residual.
template <bool FIRST, bool STORE>
__global__ __launch_bounds__(256)
void user_pass(const float* __restrict__ ent_in,
               const float* __restrict__ ucur,
               const int*   __restrict__ uoff,
               const int*   __restrict__ ucol,
               const float* __restrict__ uval,
               const float* __restrict__ latent,
               const float* __restrict__ dw,
               float*       __restrict__ emb_out,
               float*       __restrict__ res,
               const float* __restrict__ base) {
    int row  = blockIdx.x * 4 + (threadIdx.x >> 6);
    int lane = threadIdx.x & 63;
    if (row >= N_USERS) return;
    int idx = row * CH + lane;

    float u  = ucur[idx];
    float d0 = waveReduceSum(u * latent[0 * CH + lane]);
    float d1 = waveReduceSum(u * latent[1 * CH + lane]);
    float d2 = waveReduceSum(u * latent[2 * CH + lane]);
    float d3 = waveReduceSum(u * latent[3 * CH + lane]);
    float mx = fmaxf(fmaxf(d0, d1), fmaxf(d2, d3));
    float e0 = expf(d0 - mx), e1 = expf(d1 - mx), e2 = expf(d2 - mx), e3 = expf(d3 - mx);
    float inv = 1.0f / (e0 + e1 + e2 + e3);
    float mix = (e0 * dw[0 * CH + lane] + e1 * dw[1 * CH + lane] +
                 e2 * dw[2 * CH + lane] + e3 * dw[3 * CH + lane]) * inv;

    float acc = 0.0f;
    int lo = uoff[row], hi = uoff[row + 1];
    for (int k0 = lo; k0 < hi; k0 += 64) {
        int m = min(64, hi - k0);
        int   cl = (lane < m) ? ucol[k0 + lane] : 0;
        float vv = (lane < m) ? uval[k0 + lane] : 0.0f;
        for (int k = 0; k < m; ++k) {
            int   ck = __shfl(cl, k, 64);
            float vk = __shfl(vv, k, 64);
            acc += vk * ent_in[ck * CH + lane];
        }
    }
    float un = acc * (1.0f + mix);
    float s  = waveReduceSum(un * un);
    float y  = un / fmaxf(sqrtf(s), 1e-12f);
    if (STORE) emb_out[idx] = y;
    if (FIRST) res[idx] = base[idx] + y;
    else       res[idx] += y;
}

// ---------------------------------------------------------------------------
// disen_weight = softmax(att, axis=-1) @ weight   (4x8 @ 8x64 -> 4x64)
__global__ void disen_kernel(const float* __restrict__ att,
                             const float* __restrict__ weight,
                             float*       __restrict__ dw) {
    int f = threadIdx.x >> 6;
    int c = threadIdx.x & 63;
    float m = -1e30f;
    #pragma unroll
    for (int j = 0; j < N_RELM1; ++j) m = fmaxf(m, att[f * N_RELM1 + j]);
    float s = 0.0f, w[N_RELM1];
    #pragma unroll
    for (int j = 0; j < N_RELM1; ++j) { w[j] = expf(att[f * N_RELM1 + j] - m); s += w[j]; }
    float acc = 0.0f;
    #pragma unroll
    for (int j = 0; j < N_RELM1; ++j) acc += w[j] * weight[j * CH + c];
    dw[f * CH + c] = acc / s;
}

// ---------------------------------------------------------------------------
// Distance-correlation scalar over the 6 factor pairs (8x8 matrices — tiny).
__global__ void cor_kernel(const float* __restrict__ att,
                           float*       __restrict__ out) {
    if (threadIdx.x != 0 || blockIdx.x != 0) return;
    float cor = 0.0f;
    for (int i = 0; i < N_FACTORS; ++i) {
        for (int j = i + 1; j < N_FACTORS; ++j) {
            const float* t1 = att + i * N_RELM1;
            const float* t2 = att + j * N_RELM1;
            float a[8][8], b[8][8];
            for (int r = 0; r < 8; ++r)
                for (int c = 0; c < 8; ++c) {
                    float da = t1[r] * t1[r] - 2.0f * t1[r] * t1[c] + t1[c] * t1[c];
                    a[r][c] = sqrtf(fmaxf(da, 0.0f) + 1e-8f);
                    float db = t2[r] * t2[r] - 2.0f * t2[r] * t2[c] + t2[c] * t2[c];
                    b[r][c] = sqrtf(fmaxf(db, 0.0f) + 1e-8f);
                }
            float rma[8] = {0}, cma[8] = {0}, rmb[8] = {0}, cmb[8] = {0};
            float ta = 0.0f, tb = 0.0f;
            for (int r = 0; r < 8; ++r)
                for (int c = 0; c < 8; ++c) {
                    rma[r] += a[r][c]; cma[c] += a[r][c]; ta += a[r][c];
                    rmb[r] += b[r][c]; cmb[c] += b[r][c]; tb += b[r][c];
                }
            for (int r = 0; r < 8; ++r) { rma[r] *= 0.125f; rmb[r] *= 0.125f; }
            for (int c = 0; c < 8; ++c) { cma[c] *= 0.125f; cmb[c] *= 0.125f; }
            ta /= 64.0f; tb /= 64.0f;
            float sAB = 0.0f, sAA = 0.0f, sBB = 0.0f;
            for (int r = 0; r < 8; ++r)
                for (int c = 0; c < 8; ++c) {
                    float A = a[r][c] - cma[c] - rma[r] + ta;
                    float B = b[r][c] - cmb[c] - rmb[r] + tb;
                    sAB += A * B; sAA += A * A; sBB += B * B;
                }
            float dAB = sqrtf(fmaxf(sAB / 64.0f, 0.0f) + 1e-8f);
            float dAA = sqrtf(fmaxf(sAA / 64.0f, 0.0f) + 1e-8f);
            float dBB = sqrtf(fmaxf(sBB / 64.0f, 0.0f) + 1e-8f);
            cor += dAB / sqrtf(dAA * dBB + 1e-8f);
        }
    }
    out[0] = cor;
}

// ---------------------------------------------------------------------------
extern "C" void kernel_launch(void* const* d_in, const int* in_sizes, int n_in,
                              void* d_out, int out_size, void* d_ws, size_t ws_size,
                              hipStream_t stream) {
    const float* user_emb   = (const float*)d_in[0];
    const float* entity_emb = (const float*)d_in[1];
    const float* latent     = (const float*)d_in[2];
    const float* weight     = (const float*)d_in[3];
    const float* att        = (const float*)d_in[4];
    const float* ivals      = (const float*)d_in[5];
    const int*   head       = (const int*)d_in[6];
    const int*   tail       = (const int*)d_in[7];
    const int*   etype      = (const int*)d_in[8];
    const int*   irows      = (const int*)d_in[9];
    const int*   icols      = (const int*)d_in[10];

    float* out     = (float*)d_out;
    float* ent_res = out;
    float* usr_res = out + (size_t)N_ENTITIES * CH;
    float* cor_out = out + (size_t)N_ENTITIES * CH + (size_t)N_USERS * CH;

    const size_t ENT_ELEMS = (size_t)N_ENTITIES * CH;   // 6.4M
    const size_t USR_ELEMS = (size_t)N_USERS * CH;      // 3.2M

    // Workspace carve-up (~53 MB)
    float* ws   = (float*)d_ws;
    float* Ae   = ws;                               // entity emb after hop0
    float* Au   = Ae + ENT_ELEMS;                   // user emb after hop0
    float* dw   = Au + USR_ELEMS;                   // 4x64 disen weight
    int*   iws  = (int*)(dw + N_FACTORS * CH);
    int*   cntE = iws;                              // 100000
    int*   offE = cntE + N_ENTITIES;                // 100001
    int*   curE = offE + N_ENTITIES + 1;            // 100000
    int*   elst = curE + N_ENTITIES;                // 1.5M packed
    int*   cntU = elst + N_EDGES;                   // 50000
    int*   offU = cntU + N_USERS;                   // 50001
    int*   curU = offU + N_USERS + 1;               // 50000
    int*   ucol = curU + N_USERS;                   // 800K
    float* uval = (float*)(ucol + NNZ);             // 800K

    // Zero only the histograms (ws poisoned 0xAA each timed launch).
    hipMemsetAsync(cntE, 0, N_ENTITIES * sizeof(int), stream);
    hipMemsetAsync(cntU, 0, N_USERS * sizeof(int), stream);

    disen_kernel<<<1, 256, 0, stream>>>(att, weight, dw);
    cor_kernel<<<1, 64, 0, stream>>>(att, cor_out);

    // ---- Build CSR buckets (shared by both hops) ----
    hist_kernel<<<(N_EDGES + 255) / 256, 256, 0, stream>>>(head, cntE, N_EDGES);
    hist_kernel<<<(NNZ + 255) / 256, 256, 0, stream>>>(irows, cntU, NNZ);
    scan_kernel<<<1, 1024, 0, stream>>>(cntE, offE, curE, N_ENTITIES);
    scan_kernel<<<1, 1024, 0, stream>>>(cntU, offU, curU, N_USERS);
    fill_edges<<<(N_EDGES + 255) / 256, 256, 0, stream>>>(head, tail, etype, curE, elst);
    fill_users<<<(NNZ + 255) / 256, 256, 0, stream>>>(irows, icols, ivals, curU, ucol, uval);

    const int entBlocks = (N_ENTITIES + 3) / 4;
    const int usrBlocks = (N_USERS + 3) / 4;

    // ---- Hop 0 ----
    entity_pass<true, true><<<entBlocks, 256, 0, stream>>>(
        entity_emb, weight, offE, elst, Ae, ent_res, entity_emb);
    user_pass<true, true><<<usrBlocks, 256, 0, stream>>>(
        entity_emb, user_emb, offU, ucol, uval, latent, dw, Au, usr_res, user_emb);

    // ---- Hop 1 (reads hop-0 embeddings; emb store not needed) ----
    entity_pass<false, false><<<entBlocks, 256, 0, stream>>>(
        Ae, weight, offE, elst, nullptr, ent_res, nullptr);
    user_pass<false, false><<<usrBlocks, 256, 0, stream>>>(
        Ae, Au, offU, ucol, uval, latent, dw, nullptr, usr_res, nullptr);
}

// Round 3
// 645.663 us; speedup vs baseline: 1.9742x; 1.7062x over previous
//
#include <hip/hip_runtime.h>
#include <math.h>

// Problem constants (match reference)
constexpr int CH         = 64;
constexpr int N_USERS    = 50000;
constexpr int N_ENTITIES = 100000;
constexpr int N_FACTORS  = 4;
constexpr int N_RELM1    = 8;     // N_REL - 1
constexpr int N_EDGES    = 1500000;
constexpr int NNZ        = 800000;

// ---------------------------------------------------------------------------
__device__ __forceinline__ float waveReduceSum(float v) {
    #pragma unroll
    for (int off = 32; off > 0; off >>= 1)
        v += __shfl_xor(v, off, 64);
    return v;
}

// ---------------------------------------------------------------------------
// CSR build: histogram -> parallel exclusive scan -> fill (bucketed).
__global__ __launch_bounds__(256)
void hist_kernel(const int* __restrict__ key, int* __restrict__ cnt, int n) {
    int i = blockIdx.x * 256 + threadIdx.x;
    if (i < n) atomicAdd(&cnt[key[i]], 1);
}

// Pass 1: per-block (256-wide) exclusive scan; emit block sums.
__global__ __launch_bounds__(256)
void scan_partial(const int* __restrict__ cnt, int* __restrict__ off,
                  int* __restrict__ bsum, int n) {
    __shared__ int lds[256];
    int gid = blockIdx.x * 256 + threadIdx.x;
    int v = (gid < n) ? cnt[gid] : 0;
    lds[threadIdx.x] = v;
    __syncthreads();
    for (int d = 1; d < 256; d <<= 1) {
        int u = (threadIdx.x >= d) ? lds[threadIdx.x - d] : 0;
        __syncthreads();
        lds[threadIdx.x] += u;
        __syncthreads();
    }
    if (gid < n) off[gid] = lds[threadIdx.x] - v;   // block-local exclusive
    if (threadIdx.x == 255) bsum[blockIdx.x] = lds[255];
}

// Pass 2: single block scans the (<=512) block sums in-place (exclusive).
__global__ __launch_bounds__(512)
void scan_bsums(int* __restrict__ bsum, int nb) {
    __shared__ int lds[512];
    int v = (threadIdx.x < nb) ? bsum[threadIdx.x] : 0;
    lds[threadIdx.x] = v;
    __syncthreads();
    for (int d = 1; d < 512; d <<= 1) {
        int u = (threadIdx.x >= d) ? lds[threadIdx.x - d] : 0;
        __syncthreads();
        lds[threadIdx.x] += u;
        __syncthreads();
    }
    if (threadIdx.x < nb) bsum[threadIdx.x] = lds[threadIdx.x] - v;
}

// Pass 3: add block offsets; write off[0..n] (off[n]=total) and cursor copy.
__global__ __launch_bounds__(256)
void add_offsets(int* __restrict__ off, int* __restrict__ cur,
                 const int* __restrict__ bsum, int n, int total) {
    int gid = blockIdx.x * 256 + threadIdx.x;
    if (gid < n) {
        int o = off[gid] + bsum[blockIdx.x];
        off[gid] = o; cur[gid] = o;
    }
    if (gid == n) off[n] = total;
}

// Fill edge buckets with packed (tail | (etype-1)<<20).
__global__ __launch_bounds__(256)
void fill_edges(const int* __restrict__ head, const int* __restrict__ tail,
                const int* __restrict__ etype, int* __restrict__ cur,
                int* __restrict__ elist) {
    int e = blockIdx.x * 256 + threadIdx.x;
    if (e >= N_EDGES) return;
    int pos = atomicAdd(&cur[head[e]], 1);
    elist[pos] = tail[e] | ((etype[e] - 1) << 20);
}

__global__ __launch_bounds__(256)
void fill_users(const int* __restrict__ rows, const int* __restrict__ cols,
                const float* __restrict__ vals, int* __restrict__ cur,
                int* __restrict__ ucol, float* __restrict__ uval) {
    int i = blockIdx.x * 256 + threadIdx.x;
    if (i >= NNZ) return;
    int pos = atomicAdd(&cur[rows[i]], 1);
    ucol[pos] = cols[i];
    uval[pos] = vals[i];
}

// ---------------------------------------------------------------------------
// Entity pass: gather incoming-edge messages per row, L2-normalize (the /cnt
// cancels under normalization), write next-hop emb (optional) + residual.
template <bool FIRST, bool STORE>
__global__ __launch_bounds__(256)
void entity_pass(const float* __restrict__ ent_in,
                 const float* __restrict__ weight,
                 const int*   __restrict__ off,
                 const int*   __restrict__ elist,
                 float*       __restrict__ emb_out,
                 float*       __restrict__ res,
                 const float* __restrict__ base) {
    __shared__ float w_lds[N_RELM1 * CH];
    for (int i = threadIdx.x; i < N_RELM1 * CH; i += 256) w_lds[i] = weight[i];
    __syncthreads();
    int row  = blockIdx.x * 4 + (threadIdx.x >> 6);
    int lane = threadIdx.x & 63;
    if (row >= N_ENTITIES) return;
    int lo = off[row], hi = off[row + 1];
    float acc = 0.0f;
    for (int k0 = lo; k0 < hi; k0 += 64) {
        int m = min(64, hi - k0);
        int p = (lane < m) ? elist[k0 + lane] : 0;
        int k = 0;
        for (; k + 3 < m; k += 4) {      // 4 gathers in flight
            int p0 = __shfl(p, k,     64);
            int p1 = __shfl(p, k + 1, 64);
            int p2 = __shfl(p, k + 2, 64);
            int p3 = __shfl(p, k + 3, 64);
            float x0 = ent_in[(p0 & 0xFFFFF) * CH + lane];
            float x1 = ent_in[(p1 & 0xFFFFF) * CH + lane];
            float x2 = ent_in[(p2 & 0xFFFFF) * CH + lane];
            float x3 = ent_in[(p3 & 0xFFFFF) * CH + lane];
            acc += x0 * w_lds[(p0 >> 20) * CH + lane];
            acc += x1 * w_lds[(p1 >> 20) * CH + lane];
            acc += x2 * w_lds[(p2 >> 20) * CH + lane];
            acc += x3 * w_lds[(p3 >> 20) * CH + lane];
        }
        for (; k < m; ++k) {
            int pk = __shfl(p, k, 64);
            acc += ent_in[(pk & 0xFFFFF) * CH + lane] * w_lds[(pk >> 20) * CH + lane];
        }
    }
    float s = waveReduceSum(acc * acc);
    float y = acc / fmaxf(sqrtf(s), 1e-12f);
    int idx = row * CH + lane;
    if (STORE) emb_out[idx] = y;
    if (FIRST) res[idx] = base[idx] + y;
    else       res[idx] += y;
}

// ---------------------------------------------------------------------------
// User pass: gather interactions, fuse softmax(score)@dw mix, L2-norm, residual.
template <bool FIRST, bool STORE>
__global__ __launch_bounds__(256)
void user_pass(const float* __restrict__ ent_in,
               const float* __restrict__ ucur,
               const int*   __restrict__ uoff,
               const int*   __restrict__ ucol,
               const float* __restrict__ uval,
               const float* __restrict__ latent,
               const float* __restrict__ dw,
               float*       __restrict__ emb_out,
               float*       __restrict__ res,
               const float* __restrict__ base) {
    int row  = blockIdx.x * 4 + (threadIdx.x >> 6);
    int lane = threadIdx.x & 63;
    if (row >= N_USERS) return;
    int idx = row * CH + lane;

    float u  = ucur[idx];
    float d0 = waveReduceSum(u * latent[0 * CH + lane]);
    float d1 = waveReduceSum(u * latent[1 * CH + lane]);
    float d2 = waveReduceSum(u * latent[2 * CH + lane]);
    float d3 = waveReduceSum(u * latent[3 * CH + lane]);
    float mx = fmaxf(fmaxf(d0, d1), fmaxf(d2, d3));
    float e0 = expf(d0 - mx), e1 = expf(d1 - mx), e2 = expf(d2 - mx), e3 = expf(d3 - mx);
    float inv = 1.0f / (e0 + e1 + e2 + e3);
    float mix = (e0 * dw[0 * CH + lane] + e1 * dw[1 * CH + lane] +
                 e2 * dw[2 * CH + lane] + e3 * dw[3 * CH + lane]) * inv;

    float acc = 0.0f;
    int lo = uoff[row], hi = uoff[row + 1];
    for (int k0 = lo; k0 < hi; k0 += 64) {
        int m = min(64, hi - k0);
        int   cl = (lane < m) ? ucol[k0 + lane] : 0;
        float vv = (lane < m) ? uval[k0 + lane] : 0.0f;
        int k = 0;
        for (; k + 3 < m; k += 4) {
            int   c0 = __shfl(cl, k,     64);
            int   c1 = __shfl(cl, k + 1, 64);
            int   c2 = __shfl(cl, k + 2, 64);
            int   c3 = __shfl(cl, k + 3, 64);
            float v0 = __shfl(vv, k,     64);
            float v1 = __shfl(vv, k + 1, 64);
            float v2 = __shfl(vv, k + 2, 64);
            float v3 = __shfl(vv, k + 3, 64);
            float x0 = ent_in[c0 * CH + lane];
            float x1 = ent_in[c1 * CH + lane];
            float x2 = ent_in[c2 * CH + lane];
            float x3 = ent_in[c3 * CH + lane];
            acc += v0 * x0; acc += v1 * x1; acc += v2 * x2; acc += v3 * x3;
        }
        for (; k < m; ++k) {
            int   ck = __shfl(cl, k, 64);
            float vk = __shfl(vv, k, 64);
            acc += vk * ent_in[ck * CH + lane];
        }
    }
    float un = acc * (1.0f + mix);
    float s  = waveReduceSum(un * un);
    float y  = un / fmaxf(sqrtf(s), 1e-12f);
    if (STORE) emb_out[idx] = y;
    if (FIRST) res[idx] = base[idx] + y;
    else       res[idx] += y;
}

// ---------------------------------------------------------------------------
// disen_weight = softmax(att, axis=-1) @ weight   (4x8 @ 8x64 -> 4x64)
__global__ void disen_kernel(const float* __restrict__ att,
                             const float* __restrict__ weight,
                             float*       __restrict__ dw) {
    int f = threadIdx.x >> 6;
    int c = threadIdx.x & 63;
    float m = -1e30f;
    #pragma unroll
    for (int j = 0; j < N_RELM1; ++j) m = fmaxf(m, att[f * N_RELM1 + j]);
    float s = 0.0f, w[N_RELM1];
    #pragma unroll
    for (int j = 0; j < N_RELM1; ++j) { w[j] = expf(att[f * N_RELM1 + j] - m); s += w[j]; }
    float acc = 0.0f;
    #pragma unroll
    for (int j = 0; j < N_RELM1; ++j) acc += w[j] * weight[j * CH + c];
    dw[f * CH + c] = acc / s;
}

// ---------------------------------------------------------------------------
// Distance-correlation scalar over the 6 factor pairs (8x8 matrices — tiny).
__global__ void cor_kernel(const float* __restrict__ att,
                           float*       __restrict__ out) {
    if (threadIdx.x != 0 || blockIdx.x != 0) return;
    float cor = 0.0f;
    for (int i = 0; i < N_FACTORS; ++i) {
        for (int j = i + 1; j < N_FACTORS; ++j) {
            const float* t1 = att + i * N_RELM1;
            const float* t2 = att + j * N_RELM1;
            float a[8][8], b[8][8];
            for (int r = 0; r < 8; ++r)
                for (int c = 0; c < 8; ++c) {
                    float da = t1[r] * t1[r] - 2.0f * t1[r] * t1[c] + t1[c] * t1[c];
                    a[r][c] = sqrtf(fmaxf(da, 0.0f) + 1e-8f);
                    float db = t2[r] * t2[r] - 2.0f * t2[r] * t2[c] + t2[c] * t2[c];
                    b[r][c] = sqrtf(fmaxf(db, 0.0f) + 1e-8f);
                }
            float rma[8] = {0}, cma[8] = {0}, rmb[8] = {0}, cmb[8] = {0};
            float ta = 0.0f, tb = 0.0f;
            for (int r = 0; r < 8; ++r)
                for (int c = 0; c < 8; ++c) {
                    rma[r] += a[r][c]; cma[c] += a[r][c]; ta += a[r][c];
                    rmb[r] += b[r][c]; cmb[c] += b[r][c]; tb += b[r][c];
                }
            for (int r = 0; r < 8; ++r) { rma[r] *= 0.125f; rmb[r] *= 0.125f; }
            for (int c = 0; c < 8; ++c) { cma[c] *= 0.125f; cmb[c] *= 0.125f; }
            ta /= 64.0f; tb /= 64.0f;
            float sAB = 0.0f, sAA = 0.0f, sBB = 0.0f;
            for (int r = 0; r < 8; ++r)
                for (int c = 0; c < 8; ++c) {
                    float A = a[r][c] - cma[c] - rma[r] + ta;
                    float B = b[r][c] - cmb[c] - rmb[r] + tb;
                    sAB += A * B; sAA += A * A; sBB += B * B;
                }
            float dAB = sqrtf(fmaxf(sAB / 64.0f, 0.0f) + 1e-8f);
            float dAA = sqrtf(fmaxf(sAA / 64.0f, 0.0f) + 1e-8f);
            float dBB = sqrtf(fmaxf(sBB / 64.0f, 0.0f) + 1e-8f);
            cor += dAB / sqrtf(dAA * dBB + 1e-8f);
        }
    }
    out[0] = cor;
}

// ---------------------------------------------------------------------------
extern "C" void kernel_launch(void* const* d_in, const int* in_sizes, int n_in,
                              void* d_out, int out_size, void* d_ws, size_t ws_size,
                              hipStream_t stream) {
    const float* user_emb   = (const float*)d_in[0];
    const float* entity_emb = (const float*)d_in[1];
    const float* latent     = (const float*)d_in[2];
    const float* weight     = (const float*)d_in[3];
    const float* att        = (const float*)d_in[4];
    const float* ivals      = (const float*)d_in[5];
    const int*   head       = (const int*)d_in[6];
    const int*   tail       = (const int*)d_in[7];
    const int*   etype      = (const int*)d_in[8];
    const int*   irows      = (const int*)d_in[9];
    const int*   icols      = (const int*)d_in[10];

    float* out     = (float*)d_out;
    float* ent_res = out;
    float* usr_res = out + (size_t)N_ENTITIES * CH;
    float* cor_out = out + (size_t)N_ENTITIES * CH + (size_t)N_USERS * CH;

    const size_t ENT_ELEMS = (size_t)N_ENTITIES * CH;   // 6.4M
    const size_t USR_ELEMS = (size_t)N_USERS * CH;      // 3.2M

    // Workspace carve-up (~53 MB)
    float* ws   = (float*)d_ws;
    float* Ae   = ws;                               // entity emb after hop0
    float* Au   = Ae + ENT_ELEMS;                   // user emb after hop0
    float* dw   = Au + USR_ELEMS;                   // 4x64 disen weight
    int*   iws  = (int*)(dw + N_FACTORS * CH);
    int*   cntE = iws;                              // 100000
    int*   offE = cntE + N_ENTITIES;                // 100001
    int*   curE = offE + N_ENTITIES + 1;            // 100000
    int*   elst = curE + N_ENTITIES;                // 1.5M packed
    int*   cntU = elst + N_EDGES;                   // 50000
    int*   offU = cntU + N_USERS;                   // 50001
    int*   curU = offU + N_USERS + 1;               // 50000
    int*   ucol = curU + N_USERS;                   // 800K
    float* uval = (float*)(ucol + NNZ);             // 800K
    int*   bsE  = (int*)(uval + NNZ);               // <=512 block sums
    int*   bsU  = bsE + 512;                        // <=512 block sums

    // Zero only the histograms (ws poisoned 0xAA each timed launch).
    hipMemsetAsync(cntE, 0, N_ENTITIES * sizeof(int), stream);
    hipMemsetAsync(cntU, 0, N_USERS * sizeof(int), stream);

    disen_kernel<<<1, 256, 0, stream>>>(att, weight, dw);
    cor_kernel<<<1, 64, 0, stream>>>(att, cor_out);

    // ---- Build CSR buckets (shared by both hops) ----
    hist_kernel<<<(N_EDGES + 255) / 256, 256, 0, stream>>>(head, cntE, N_EDGES);
    hist_kernel<<<(NNZ + 255) / 256, 256, 0, stream>>>(irows, cntU, NNZ);

    const int nbE = (N_ENTITIES + 255) / 256;   // 391
    const int nbU = (N_USERS + 255) / 256;      // 196
    scan_partial<<<nbE, 256, 0, stream>>>(cntE, offE, bsE, N_ENTITIES);
    scan_partial<<<nbU, 256, 0, stream>>>(cntU, offU, bsU, N_USERS);
    scan_bsums<<<1, 512, 0, stream>>>(bsE, nbE);
    scan_bsums<<<1, 512, 0, stream>>>(bsU, nbU);
    add_offsets<<<nbE + 1, 256, 0, stream>>>(offE, curE, bsE, N_ENTITIES, N_EDGES);
    add_offsets<<<nbU + 1, 256, 0, stream>>>(offU, curU, bsU, N_USERS, NNZ);

    fill_edges<<<(N_EDGES + 255) / 256, 256, 0, stream>>>(head, tail, etype, curE, elst);
    fill_users<<<(NNZ + 255) / 256, 256, 0, stream>>>(irows, icols, ivals, curU, ucol, uval);

    const int entBlocks = (N_ENTITIES + 3) / 4;
    const int usrBlocks = (N_USERS + 3) / 4;

    // ---- Hop 0 ----
    entity_pass<true, true><<<entBlocks, 256, 0, stream>>>(
        entity_emb, weight, offE, elst, Ae, ent_res, entity_emb);
    user_pass<true, true><<<usrBlocks, 256, 0, stream>>>(
        entity_emb, user_emb, offU, ucol, uval, latent, dw, Au, usr_res, user_emb);

    // ---- Hop 1 (reads hop-0 embeddings; emb store not needed) ----
    entity_pass<false, false><<<entBlocks, 256, 0, stream>>>(
        Ae, weight, offE, elst, nullptr, ent_res, nullptr);
    user_pass<false, false><<<usrBlocks, 256, 0, stream>>>(
        Ae, Au, offU, ucol, uval, latent, dw, nullptr, usr_res, nullptr);
}

// Round 4
// 613.530 us; speedup vs baseline: 2.0776x; 1.0524x over previous
//
#include <hip/hip_runtime.h>
#include <math.h>

// Problem constants (match reference)
constexpr int CH         = 64;
constexpr int N_USERS    = 50000;
constexpr int N_ENTITIES = 100000;
constexpr int N_FACTORS  = 4;
constexpr int N_RELM1    = 8;     // N_REL - 1
constexpr int N_EDGES    = 1500000;
constexpr int NNZ        = 800000;

constexpr int NBE        = (N_ENTITIES + 255) / 256;  // 391 scan blocks (E)
constexpr int NBU        = (N_USERS + 255) / 256;     // 196 scan blocks (U)
constexpr int TOTAL      = N_EDGES + NNZ;             // 2.3M fill items
constexpr int ENT_BLOCKS = N_ENTITIES / 4;            // 25000 (exact)
constexpr int USR_BLOCKS = N_USERS / 4;               // 12500 (exact)

// ---------------------------------------------------------------------------
__device__ __forceinline__ float waveReduceSum(float v) {
    #pragma unroll
    for (int off = 32; off > 0; off >>= 1)
        v += __shfl_xor(v, off, 64);
    return v;
}

// ---------------------------------------------------------------------------
// Fused histogram: items [0,N_EDGES) -> cntE[head], rest -> cntU[irows].
// 4 items/thread, loads hoisted so 4 atomics are in flight per lane.
__global__ __launch_bounds__(256)
void hist_all(const int* __restrict__ head, const int* __restrict__ irows,
              int* __restrict__ cntE, int* __restrict__ cntU) {
    int t  = blockIdx.x * 256 + threadIdx.x;
    int NT = gridDim.x * 256;
    int  k[4]; bool val[4], isE[4];
    #pragma unroll
    for (int j = 0; j < 4; ++j) {
        int i = t + j * NT;
        val[j] = i < TOTAL;
        isE[j] = i < N_EDGES;
        k[j] = 0;
        if (val[j]) k[j] = isE[j] ? head[i] : irows[i - N_EDGES];
    }
    #pragma unroll
    for (int j = 0; j < 4; ++j)
        if (val[j]) atomicAdd(isE[j] ? &cntE[k[j]] : &cntU[k[j]], 1);
}

// ---------------------------------------------------------------------------
// Scan pass 1: per-block exclusive scan of cntE/cntU; emit block sums.
__global__ __launch_bounds__(256)
void scan_partial(const int* __restrict__ cntE, const int* __restrict__ cntU,
                  int* __restrict__ offE, int* __restrict__ offU,
                  int* __restrict__ bsum) {
    __shared__ int lds[256];
    int b = blockIdx.x;
    const int* src; int* dst; int n, lb;
    if (b < NBE) { src = cntE; dst = offE; n = N_ENTITIES; lb = b; }
    else         { src = cntU; dst = offU; n = N_USERS;    lb = b - NBE; }
    int gid = lb * 256 + threadIdx.x;
    int v = (gid < n) ? src[gid] : 0;
    lds[threadIdx.x] = v;
    __syncthreads();
    for (int d = 1; d < 256; d <<= 1) {
        int u = (threadIdx.x >= d) ? lds[threadIdx.x - d] : 0;
        __syncthreads();
        lds[threadIdx.x] += u;
        __syncthreads();
    }
    if (gid < n) dst[gid] = lds[threadIdx.x] - v;
    if (threadIdx.x == 255) bsum[b] = lds[255];
}

// Scan pass 2: block 0 scans bsum[0..NBE), block 1 scans bsum[NBE..NBE+NBU).
__global__ __launch_bounds__(512)
void scan_bsums(int* __restrict__ bsum) {
    __shared__ int lds[512];
    int base = (blockIdx.x == 0) ? 0   : NBE;
    int nb   = (blockIdx.x == 0) ? NBE : NBU;
    int v = (threadIdx.x < nb) ? bsum[base + threadIdx.x] : 0;
    lds[threadIdx.x] = v;
    __syncthreads();
    for (int d = 1; d < 512; d <<= 1) {
        int u = (threadIdx.x >= d) ? lds[threadIdx.x - d] : 0;
        __syncthreads();
        lds[threadIdx.x] += u;
        __syncthreads();
    }
    if (threadIdx.x < nb) bsum[base + threadIdx.x] = lds[threadIdx.x] - v;
}

// Scan pass 3: add block offsets, write off[] + cursor copy + off[n]=total.
__global__ __launch_bounds__(256)
void add_offsets(int* __restrict__ offE, int* __restrict__ curE,
                 int* __restrict__ offU, int* __restrict__ curU,
                 const int* __restrict__ bsum) {
    int b = blockIdx.x;
    int* off; int* cur; int n, lb, total;
    if (b < NBE) { off = offE; cur = curE; n = N_ENTITIES; lb = b;       total = N_EDGES; }
    else         { off = offU; cur = curU; n = N_USERS;    lb = b - NBE; total = NNZ; }
    int gid = lb * 256 + threadIdx.x;
    if (gid < n) {
        int o = off[gid] + bsum[b];
        off[gid] = o; cur[gid] = o;
    }
    if (gid == n) off[n] = total;
}

// ---------------------------------------------------------------------------
// Fused fill: edges -> elst (packed tail|(etype-1)<<20), users -> ucol/uval.
// 4 items/thread with hoisted loads: 4 independent atomic->store chains.
__global__ __launch_bounds__(256)
void fill_all(const int* __restrict__ head, const int* __restrict__ tail,
              const int* __restrict__ etype,
              const int* __restrict__ irows, const int* __restrict__ icols,
              const float* __restrict__ ivals,
              int* __restrict__ curE, int* __restrict__ curU,
              int* __restrict__ elst, int* __restrict__ ucol,
              float* __restrict__ uval) {
    int t  = blockIdx.x * 256 + threadIdx.x;
    int NT = gridDim.x * 256;
    int key[4], pay[4]; float pv[4]; bool val[4], isE[4];
    #pragma unroll
    for (int j = 0; j < 4; ++j) {
        int i = t + j * NT;
        val[j] = i < TOTAL;
        isE[j] = i < N_EDGES;
        key[j] = 0; pay[j] = 0; pv[j] = 0.0f;
        if (val[j]) {
            if (isE[j]) { key[j] = head[i]; pay[j] = tail[i] | ((etype[i] - 1) << 20); }
            else { int ii = i - N_EDGES; key[j] = irows[ii]; pay[j] = icols[ii]; pv[j] = ivals[ii]; }
        }
    }
    #pragma unroll
    for (int j = 0; j < 4; ++j) {
        if (!val[j]) continue;
        if (isE[j]) {
            int pos = atomicAdd(&curE[key[j]], 1);
            elst[pos] = pay[j];
        } else {
            int pos = atomicAdd(&curU[key[j]], 1);
            ucol[pos] = pay[j];
            uval[pos] = pv[j];
        }
    }
}

// ---------------------------------------------------------------------------
// Fused per-hop pass: blocks [0,ENT_BLOCKS) do entity rows, rest do users.
// Entity: gather + L2-normalize (the /cnt cancels under normalization).
// User: gather + softmax(score)@dw mix + L2-normalize. Both add residual.
template <bool HOP0>
__global__ __launch_bounds__(256)
void hop_pass(const float* __restrict__ ent_in, const float* __restrict__ usr_in,
              const float* __restrict__ weight, const float* __restrict__ latent,
              const float* __restrict__ dw,
              const int* __restrict__ offE, const int* __restrict__ elst,
              const int* __restrict__ offU, const int* __restrict__ ucol,
              const float* __restrict__ uval,
              float* __restrict__ Ae_out, float* __restrict__ Au_out,
              float* __restrict__ ent_res, float* __restrict__ usr_res,
              const float* __restrict__ ent_base, const float* __restrict__ usr_base) {
    __shared__ float w_lds[N_RELM1 * CH];
    int lane = threadIdx.x & 63;
    if (blockIdx.x < ENT_BLOCKS) {
        for (int i = threadIdx.x; i < N_RELM1 * CH; i += 256) w_lds[i] = weight[i];
        __syncthreads();
        int row = blockIdx.x * 4 + (threadIdx.x >> 6);
        int lo = offE[row], hi = offE[row + 1];
        float acc = 0.0f;
        for (int k0 = lo; k0 < hi; k0 += 64) {
            int m = min(64, hi - k0);
            int p = (lane < m) ? elst[k0 + lane] : 0;
            int k = 0;
            for (; k + 3 < m; k += 4) {      // 4 gathers in flight
                int p0 = __shfl(p, k,     64);
                int p1 = __shfl(p, k + 1, 64);
                int p2 = __shfl(p, k + 2, 64);
                int p3 = __shfl(p, k + 3, 64);
                float x0 = ent_in[(p0 & 0xFFFFF) * CH + lane];
                float x1 = ent_in[(p1 & 0xFFFFF) * CH + lane];
                float x2 = ent_in[(p2 & 0xFFFFF) * CH + lane];
                float x3 = ent_in[(p3 & 0xFFFFF) * CH + lane];
                acc += x0 * w_lds[(p0 >> 20) * CH + lane];
                acc += x1 * w_lds[(p1 >> 20) * CH + lane];
                acc += x2 * w_lds[(p2 >> 20) * CH + lane];
                acc += x3 * w_lds[(p3 >> 20) * CH + lane];
            }
            for (; k < m; ++k) {
                int pk = __shfl(p, k, 64);
                acc += ent_in[(pk & 0xFFFFF) * CH + lane] * w_lds[(pk >> 20) * CH + lane];
            }
        }
        float s = waveReduceSum(acc * acc);
        float y = acc / fmaxf(sqrtf(s), 1e-12f);
        int idx = row * CH + lane;
        if (HOP0) { Ae_out[idx] = y; ent_res[idx] = ent_base[idx] + y; }
        else      { ent_res[idx] += y; }
    } else {
        int row = (blockIdx.x - ENT_BLOCKS) * 4 + (threadIdx.x >> 6);
        int idx = row * CH + lane;
        float u  = usr_in[idx];
        float d0 = waveReduceSum(u * latent[0 * CH + lane]);
        float d1 = waveReduceSum(u * latent[1 * CH + lane]);
        float d2 = waveReduceSum(u * latent[2 * CH + lane]);
        float d3 = waveReduceSum(u * latent[3 * CH + lane]);
        float mx = fmaxf(fmaxf(d0, d1), fmaxf(d2, d3));
        float e0 = expf(d0 - mx), e1 = expf(d1 - mx), e2 = expf(d2 - mx), e3 = expf(d3 - mx);
        float inv = 1.0f / (e0 + e1 + e2 + e3);
        float mix = (e0 * dw[0 * CH + lane] + e1 * dw[1 * CH + lane] +
                     e2 * dw[2 * CH + lane] + e3 * dw[3 * CH + lane]) * inv;
        float acc = 0.0f;
        int lo = offU[row], hi = offU[row + 1];
        for (int k0 = lo; k0 < hi; k0 += 64) {
            int m = min(64, hi - k0);
            int   cl = (lane < m) ? ucol[k0 + lane] : 0;
            float vv = (lane < m) ? uval[k0 + lane] : 0.0f;
            int k = 0;
            for (; k + 3 < m; k += 4) {
                int   c0 = __shfl(cl, k,     64);
                int   c1 = __shfl(cl, k + 1, 64);
                int   c2 = __shfl(cl, k + 2, 64);
                int   c3 = __shfl(cl, k + 3, 64);
                float v0 = __shfl(vv, k,     64);
                float v1 = __shfl(vv, k + 1, 64);
                float v2 = __shfl(vv, k + 2, 64);
                float v3 = __shfl(vv, k + 3, 64);
                float x0 = ent_in[c0 * CH + lane];
                float x1 = ent_in[c1 * CH + lane];
                float x2 = ent_in[c2 * CH + lane];
                float x3 = ent_in[c3 * CH + lane];
                acc += v0 * x0; acc += v1 * x1; acc += v2 * x2; acc += v3 * x3;
            }
            for (; k < m; ++k) {
                int   ck = __shfl(cl, k, 64);
                float vk = __shfl(vv, k, 64);
                acc += vk * ent_in[ck * CH + lane];
            }
        }
        float un = acc * (1.0f + mix);
        float s  = waveReduceSum(un * un);
        float y  = un / fmaxf(sqrtf(s), 1e-12f);
        if (HOP0) { Au_out[idx] = y; usr_res[idx] = usr_base[idx] + y; }
        else      { usr_res[idx] += y; }
    }
}

// ---------------------------------------------------------------------------
// Block 0: disen_weight = softmax(att,-1) @ weight (4x8 @ 8x64).
// Block 1: distance-correlation, one wave per factor pair, lane = (r,c) of 8x8.
__global__ __launch_bounds__(384)
void discor_kernel(const float* __restrict__ att,
                   const float* __restrict__ weight,
                   float* __restrict__ dw,
                   float* __restrict__ cor_out) {
    __shared__ float part[6];
    if (blockIdx.x == 0) {
        if (threadIdx.x < 256) {
            int f = threadIdx.x >> 6;
            int c = threadIdx.x & 63;
            float m = -1e30f;
            #pragma unroll
            for (int j = 0; j < N_RELM1; ++j) m = fmaxf(m, att[f * N_RELM1 + j]);
            float s = 0.0f, w[N_RELM1];
            #pragma unroll
            for (int j = 0; j < N_RELM1; ++j) { w[j] = expf(att[f * N_RELM1 + j] - m); s += w[j]; }
            float acc = 0.0f;
            #pragma unroll
            for (int j = 0; j < N_RELM1; ++j) acc += w[j] * weight[j * CH + c];
            dw[f * CH + c] = acc / s;
        }
    } else {
        int w    = threadIdx.x >> 6;   // 0..5 = pair index
        int lane = threadIdx.x & 63;
        const int pi[6] = {0, 0, 0, 1, 1, 2};
        const int pj[6] = {1, 2, 3, 2, 3, 3};
        int r = lane >> 3, c = lane & 7;
        const float* t1 = att + pi[w] * N_RELM1;
        const float* t2 = att + pj[w] * N_RELM1;
        float a  = sqrtf(fmaxf(t1[r] * t1[r] - 2.0f * t1[r] * t1[c] + t1[c] * t1[c], 0.0f) + 1e-8f);
        float bb = sqrtf(fmaxf(t2[r] * t2[r] - 2.0f * t2[r] * t2[c] + t2[c] * t2[c], 0.0f) + 1e-8f);
        // row sums (over c: xor 1,2,4) and col sums (over r: xor 8,16,32)
        float rsA = a, rsB = bb;
        #pragma unroll
        for (int o = 1; o < 8; o <<= 1) { rsA += __shfl_xor(rsA, o, 64); rsB += __shfl_xor(rsB, o, 64); }
        float csA = a, csB = bb;
        #pragma unroll
        for (int o = 8; o < 64; o <<= 1) { csA += __shfl_xor(csA, o, 64); csB += __shfl_xor(csB, o, 64); }
        float totA = rsA, totB = rsB;
        #pragma unroll
        for (int o = 8; o < 64; o <<= 1) { totA += __shfl_xor(totA, o, 64); totB += __shfl_xor(totB, o, 64); }
        float A = a  - csA * 0.125f - rsA * 0.125f + totA * (1.0f / 64.0f);
        float B = bb - csB * 0.125f - rsB * 0.125f + totB * (1.0f / 64.0f);
        float sAB = A * B, sAA = A * A, sBB = B * B;
        #pragma unroll
        for (int o = 1; o < 64; o <<= 1) {
            sAB += __shfl_xor(sAB, o, 64);
            sAA += __shfl_xor(sAA, o, 64);
            sBB += __shfl_xor(sBB, o, 64);
        }
        if (lane == 0) {
            float dAB = sqrtf(fmaxf(sAB * (1.0f / 64.0f), 0.0f) + 1e-8f);
            float dAA = sqrtf(fmaxf(sAA * (1.0f / 64.0f), 0.0f) + 1e-8f);
            float dBB = sqrtf(fmaxf(sBB * (1.0f / 64.0f), 0.0f) + 1e-8f);
            part[w] = dAB / sqrtf(dAA * dBB + 1e-8f);
        }
        __syncthreads();
        if (threadIdx.x == 0) {
            float s = 0.0f;
            for (int q = 0; q < 6; ++q) s += part[q];
            cor_out[0] = s;
        }
    }
}

// ---------------------------------------------------------------------------
extern "C" void kernel_launch(void* const* d_in, const int* in_sizes, int n_in,
                              void* d_out, int out_size, void* d_ws, size_t ws_size,
                              hipStream_t stream) {
    const float* user_emb   = (const float*)d_in[0];
    const float* entity_emb = (const float*)d_in[1];
    const float* latent     = (const float*)d_in[2];
    const float* weight     = (const float*)d_in[3];
    const float* att        = (const float*)d_in[4];
    const float* ivals      = (const float*)d_in[5];
    const int*   head       = (const int*)d_in[6];
    const int*   tail       = (const int*)d_in[7];
    const int*   etype      = (const int*)d_in[8];
    const int*   irows      = (const int*)d_in[9];
    const int*   icols      = (const int*)d_in[10];

    float* out     = (float*)d_out;
    float* ent_res = out;
    float* usr_res = out + (size_t)N_ENTITIES * CH;
    float* cor_out = out + (size_t)N_ENTITIES * CH + (size_t)N_USERS * CH;

    const size_t ENT_ELEMS = (size_t)N_ENTITIES * CH;   // 6.4M
    const size_t USR_ELEMS = (size_t)N_USERS * CH;      // 3.2M

    // Workspace carve-up (~53 MB)
    float* ws   = (float*)d_ws;
    float* Ae   = ws;                               // entity emb after hop0
    float* Au   = Ae + ENT_ELEMS;                   // user emb after hop0
    float* dw   = Au + USR_ELEMS;                   // 4x64 disen weight
    int*   cntE = (int*)(dw + N_FACTORS * CH);      // 100000  (contiguous with
    int*   cntU = cntE + N_ENTITIES;                // 50000    cntU: one memset)
    int*   offE = cntU + N_USERS;                   // 100001
    int*   curE = offE + N_ENTITIES + 1;            // 100000
    int*   offU = curE + N_ENTITIES;                // 50001
    int*   curU = offU + N_USERS + 1;               // 50000
    int*   bsum = curU + N_USERS;                   // 1024 (NBE+NBU=587)
    int*   elst = bsum + 1024;                      // 1.5M packed
    int*   ucol = elst + N_EDGES;                   // 800K
    float* uval = (float*)(ucol + NNZ);             // 800K

    // Zero only the histograms (single contiguous memset).
    hipMemsetAsync(cntE, 0, (N_ENTITIES + N_USERS) * sizeof(int), stream);

    discor_kernel<<<2, 384, 0, stream>>>(att, weight, dw, cor_out);

    // ---- Build CSR buckets (shared by both hops) ----
    const int hb = (TOTAL + 1023) / 1024;   // 4 items/thread
    hist_all<<<hb, 256, 0, stream>>>(head, irows, cntE, cntU);
    scan_partial<<<NBE + NBU, 256, 0, stream>>>(cntE, cntU, offE, offU, bsum);
    scan_bsums<<<2, 512, 0, stream>>>(bsum);
    add_offsets<<<NBE + NBU, 256, 0, stream>>>(offE, curE, offU, curU, bsum);
    fill_all<<<hb, 256, 0, stream>>>(head, tail, etype, irows, icols, ivals,
                                     curE, curU, elst, ucol, uval);

    // ---- Hop 0 (reads input embeddings) ----
    hop_pass<true><<<ENT_BLOCKS + USR_BLOCKS, 256, 0, stream>>>(
        entity_emb, user_emb, weight, latent, dw,
        offE, elst, offU, ucol, uval,
        Ae, Au, ent_res, usr_res, entity_emb, user_emb);

    // ---- Hop 1 (reads hop-0 embeddings) ----
    hop_pass<false><<<ENT_BLOCKS + USR_BLOCKS, 256, 0, stream>>>(
        Ae, Au, weight, latent, dw,
        offE, elst, offU, ucol, uval,
        nullptr, nullptr, ent_res, usr_res, nullptr, nullptr);
}